// Round 8
// baseline (77.334 us; speedup 1.0000x reference)
//
#include <hip/hip_runtime.h>
#include <math.h>

#define HW 262144            // 512*512
#define TOTAL 12582912       // 48 planes * HW
#define TS 32
#define NT 512               // threads per block
#define P 2                  // planes per block, element-interleaved as float2
#define NGROUP 24            // 48 / P

#define CR 0.8910065241883679f   // cos(27 deg)
#define SR 0.45399049973954675f  // sin(27 deg)

#define K5CX (255.5f * (1.0f - CR + SR))
#define K5CY (255.5f * (1.0f - SR - CR))

// Fixed padded region dims (>= max true span at any tile position)
#define W2 52
#define H2 44
#define W3 46
#define H3 45
#define W4 49
#define H4 48
#define W5 36
#define H5 35
#define BUFA_SZ 2352   // float2 cells: max(W2*H2=2288, W4*H4=2352)
#define BUFB_SZ 2070   // float2 cells: max(W3*H3=2070, W5*H5=1260)

struct Box { int x0, x1, y0, y1; };

__device__ __forceinline__ Box back_box(Box d, float A, float B, float C,
                                        float D, float E, float F) {
    float xa = (float)d.x0, xb = (float)d.x1, ya = (float)d.y0, yb = (float)d.y1;
    float mnx = fminf(A * xa, A * xb) + fminf(B * ya, B * yb) + C;
    float mxx = fmaxf(A * xa, A * xb) + fmaxf(B * ya, B * yb) + C;
    float mny = fminf(D * xa, D * xb) + fminf(E * ya, E * yb) + F;
    float mxy = fmaxf(D * xa, D * xb) + fmaxf(E * ya, E * yb) + F;
    Box s;
    s.x0 = (int)floorf(mnx); s.x1 = (int)floorf(mxx) + 1;
    s.y0 = (int)floorf(mny); s.y1 = (int)floorf(mxy) + 1;
    return s;
}

__device__ __forceinline__ float2 lerp2(float w, float2 a, float2 b) {
    float2 r;
    r.x = fmaf(w, b.x - a.x, a.x);
    r.y = fmaf(w, b.y - a.y, a.y);
    return r;
}

// ---- geometry for one LDS-stage item ----
template <int SW, int SH, int DW, bool AXIS, bool INT>
__device__ __forceinline__ void lds_geom(int i, float A, float B, float Cs,
    float D, float E, float Fs, int dx0, int dy0,
    int& sbase, float& wx, float& wy, bool& oob)
{
    int ly = i / DW;
    int lx = i - ly * DW;
    int pxi = dx0 + lx, pyi = dy0 + ly;
    float px = (float)pxi, py = (float)pyi;
    float fx = AXIS ? fmaf(A, px, Cs) : fmaf(A, px, fmaf(B, py, Cs));
    float fy = AXIS ? fmaf(E, py, Fs) : fmaf(D, px, fmaf(E, py, Fs));
    float xf = floorf(fx), yf = floorf(fy);
    wx = fx - xf; wy = fy - yf;
    int x0 = (int)xf, y0 = (int)yf;
    if (!INT) { x0 = min(max(x0, 0), SW - 2); y0 = min(max(y0, 0), SH - 2); }
    sbase = y0 * SW + x0;
    oob = (!INT) && ((unsigned)pxi >= 512u || (unsigned)pyi >= 512u);
}

// ---- LDS -> LDS bilinear stage, pair-batched for read ILP ----
template <int SW, int SH, int DW, int DTOT, bool AXIS, bool INT>
__device__ __forceinline__ void stage_lds(int tid, float A, float B, float Cs,
    float D, float E, float Fs, const float2* __restrict__ src,
    float2* __restrict__ dst, int dx0, int dy0)
{
    constexpr int NITEM = (DTOT + NT - 1) / NT;
    #pragma unroll
    for (int k = 0; k < NITEM; k += 2) {
        constexpr int KMAX = NITEM;        // for constexpr-friendly guard
        const bool HAS1 = (k + 1 < KMAX);
        int i0 = tid + k * NT;
        int i1 = i0 + NT;
        bool w0 = (i0 < DTOT);
        bool w1 = HAS1 && (i1 < DTOT);
        int c0 = min(i0, DTOT - 1);
        int c1 = min(i1, DTOT - 1);

        int s0, s1 = 0; float wx0, wy0, wx1 = 0.f, wy1 = 0.f; bool o0, o1 = false;
        lds_geom<SW, SH, DW, AXIS, INT>(c0, A, B, Cs, D, E, Fs, dx0, dy0,
                                        s0, wx0, wy0, o0);
        if (HAS1)
            lds_geom<SW, SH, DW, AXIS, INT>(c1, A, B, Cs, D, E, Fs, dx0, dy0,
                                            s1, wx1, wy1, o1);

        // issue all reads back-to-back (independent chains)
        float2 q00 = src[s0], q01 = src[s0 + 1];
        float2 q10 = src[s0 + SW], q11 = src[s0 + SW + 1];
        float2 r00, r01, r10, r11;
        if (HAS1) { r00 = src[s1]; r01 = src[s1 + 1];
                    r10 = src[s1 + SW]; r11 = src[s1 + SW + 1]; }

        {
            float2 a0 = lerp2(wx0, q00, q01);
            float2 a1 = lerp2(wx0, q10, q11);
            float2 val = lerp2(wy0, a0, a1);
            if (!INT && o0) { val.x = 0.f; val.y = 0.f; }
            if (w0) dst[c0] = val;
        }
        if (HAS1) {
            float2 a0 = lerp2(wx1, r00, r01);
            float2 a1 = lerp2(wx1, r10, r11);
            float2 val = lerp2(wy1, a0, a1);
            if (!INT && o1) { val.x = 0.f; val.y = 0.f; }
            if (w1) dst[c1] = val;
        }
    }
}

// ---- stage 2 (translate, mirror folded): global -> bufA, pair-batched ----
// Constant weights wx=0.36, wy=0.76; taps at x = 496-pxi, 495-pxi; rows pyi-11, pyi-10.
template <bool INT>
__device__ __forceinline__ void s2_geom(int i, int rx0, int ry0,
    int& off0, int& off1, float& wx0m, float& wx1m, float& wy0m, float& wy1m)
{
    int ly = i / W2;
    int lx = i - ly * W2;
    int pxi = rx0 + lx, pyi = ry0 + ly;
    if (INT) {
        off0 = ((pyi - 11) << 9) + (496 - pxi);
        off1 = off0;  // unused split
        wx0m = 0.64f; wx1m = 0.36f; wy0m = 0.24f; wy1m = 0.76f;
    } else {
        wx0m = ((unsigned)pxi <= 496u) ? 0.64f : 0.0f;
        wx1m = ((unsigned)pxi <= 495u) ? 0.36f : 0.0f;
        wy0m = ((unsigned)(pyi - 11) <= 500u) ? 0.24f : 0.0f;
        wy1m = ((unsigned)(pyi - 10) <= 501u) ? 0.76f : 0.0f;
        int xc0 = min(max(496 - pxi, 0), 511);
        int r0 = min(max(pyi - 11, 0), 511) << 9;
        int r1 = min(max(pyi - 10, 0), 511) << 9;
        off0 = r0 + xc0;                       // x1 tap = off-1 clamped below
        off1 = r1 + xc0;
        // x1 index handled via xc1 = min(max(495-pxi,0),511) = xc0-1 except clamp edges
    }
}

template <bool INT>
__device__ __forceinline__ void s2_pair(int tid, int k, const float* __restrict__ gin,
                                        float2* __restrict__ dst, int rx0, int ry0,
                                        bool has1)
{
    int i0 = tid + k * NT;
    int i1 = i0 + NT;
    bool w0 = (i0 < W2 * H2);
    bool w1 = has1 && (i1 < W2 * H2);
    int c0 = min(i0, W2 * H2 - 1);
    int c1 = min(i1, W2 * H2 - 1);

    if (INT) {
        int ly0 = c0 / W2, lx0 = c0 - ly0 * W2;
        int ly1 = c1 / W2, lx1 = c1 - ly1 * W2;
        int offA = ((ry0 + ly0 - 11) << 9) + (496 - (rx0 + lx0));
        int offB = ((ry0 + ly1 - 11) << 9) + (496 - (rx0 + lx1));
        const float* gA0 = gin + offA;
        const float* gA1 = gin + HW + offA;
        const float* gB0 = gin + offB;
        const float* gB1 = gin + HW + offB;
        // issue 16 loads back-to-back
        float a00 = gA0[0], a01 = gA0[-1], a02 = gA0[512], a03 = gA0[511];
        float a10 = gA1[0], a11 = gA1[-1], a12 = gA1[512], a13 = gA1[511];
        float b00 = 0.f, b01 = 0.f, b02 = 0.f, b03 = 0.f;
        float b10 = 0.f, b11 = 0.f, b12 = 0.f, b13 = 0.f;
        if (has1) {
            b00 = gB0[0]; b01 = gB0[-1]; b02 = gB0[512]; b03 = gB0[511];
            b10 = gB1[0]; b11 = gB1[-1]; b12 = gB1[512]; b13 = gB1[511];
        }
        float2 o0, o1;
        o0.x = fmaf(0.76f, fmaf(0.36f, a03, 0.64f * a02),
                    0.24f * fmaf(0.36f, a01, 0.64f * a00));
        o0.y = fmaf(0.76f, fmaf(0.36f, a13, 0.64f * a12),
                    0.24f * fmaf(0.36f, a11, 0.64f * a10));
        if (w0) dst[c0] = o0;
        if (has1) {
            o1.x = fmaf(0.76f, fmaf(0.36f, b03, 0.64f * b02),
                        0.24f * fmaf(0.36f, b01, 0.64f * b00));
            o1.y = fmaf(0.76f, fmaf(0.36f, b13, 0.64f * b12),
                        0.24f * fmaf(0.36f, b11, 0.64f * b10));
            if (w1) dst[c1] = o1;
        }
    } else {
        // boundary path: per-item full validity logic (rare tiles)
        #pragma unroll
        for (int t = 0; t < 2; ++t) {
            if (t == 1 && !has1) break;
            int c = (t == 0) ? c0 : c1;
            bool w = (t == 0) ? w0 : w1;
            int ly = c / W2, lx = c - ly * W2;
            int pxi = rx0 + lx, pyi = ry0 + ly;
            float wx0m = ((unsigned)pxi <= 496u) ? 0.64f : 0.0f;
            float wx1m = ((unsigned)pxi <= 495u) ? 0.36f : 0.0f;
            float wy0m = ((unsigned)(pyi - 11) <= 500u) ? 0.24f : 0.0f;
            float wy1m = ((unsigned)(pyi - 10) <= 501u) ? 0.76f : 0.0f;
            int xc0 = min(max(496 - pxi, 0), 511);
            int xc1 = min(max(495 - pxi, 0), 511);
            int r0 = min(max(pyi - 11, 0), 511) << 9;
            int r1 = min(max(pyi - 10, 0), 511) << 9;
            float2 o;
            #pragma unroll
            for (int p = 0; p < P; ++p) {
                const float* g = gin + p * HW;
                float v00 = g[r0 + xc0], v01 = g[r0 + xc1];
                float v10 = g[r1 + xc0], v11 = g[r1 + xc1];
                float h0 = fmaf(wx1m, v01, wx0m * v00);
                float h1 = fmaf(wx1m, v11, wx0m * v10);
                float val = fmaf(wy1m, h1, wy0m * h0);
                if (p == 0) o.x = val; else o.y = val;
            }
            if (w) dst[c] = o;
        }
    }
}

// ---- stage 6 (shear): bufB(R5, float2) -> global, both items batched ----
template <bool INT>
__device__ __forceinline__ void s6_both(int tid, const float2* __restrict__ src,
    float* __restrict__ go, int tx0, int ty0, int sx0, int sy0)
{
    float Csx = -12.775f - (float)sx0;
    float Fsy = 7.665f - (float)sy0;
    int s[2]; float wx[2], wy[2]; int gidx[2];
    #pragma unroll
    for (int t = 0; t < 2; ++t) {
        int ii = tid + t * NT;
        int lx = ii & 31, ly = ii >> 5;
        float px = (float)(tx0 + lx), py = (float)(ty0 + ly);
        float fx = fmaf(0.05f, py, Csx) + px;
        float fy = fmaf(-0.03f, px, Fsy) + py;
        float xf = floorf(fx), yf = floorf(fy);
        wx[t] = fx - xf; wy[t] = fy - yf;
        int x0 = (int)xf, y0 = (int)yf;
        if (!INT) { x0 = min(max(x0, 0), W5 - 2); y0 = min(max(y0, 0), H5 - 2); }
        s[t] = y0 * W5 + x0;
        gidx[t] = (ty0 + ly) * 512 + tx0 + lx;
    }
    float2 q00 = src[s[0]], q01 = src[s[0] + 1];
    float2 q10 = src[s[0] + W5], q11 = src[s[0] + W5 + 1];
    float2 r00 = src[s[1]], r01 = src[s[1] + 1];
    float2 r10 = src[s[1] + W5], r11 = src[s[1] + W5 + 1];
    {
        float2 a0 = lerp2(wx[0], q00, q01);
        float2 a1 = lerp2(wx[0], q10, q11);
        float2 val = lerp2(wy[0], a0, a1);
        __builtin_nontemporal_store(val.x, &go[gidx[0]]);
        __builtin_nontemporal_store(val.y, &go[HW + gidx[0]]);
    }
    {
        float2 a0 = lerp2(wx[1], r00, r01);
        float2 a1 = lerp2(wx[1], r10, r11);
        float2 val = lerp2(wy[1], a0, a1);
        __builtin_nontemporal_store(val.x, &go[gidx[1]]);
        __builtin_nontemporal_store(val.y, &go[HW + gidx[1]]);
    }
}

// ---- full img tile pipeline for 2 interleaved planes ----
template <bool INT>
__device__ __forceinline__ void img_tile(int tid, const float* __restrict__ gin,
    float* __restrict__ go, int tx0, int ty0,
    Box R2, Box R3, Box R4, Box R5, float2* bufA, float2* bufB)
{
    // stage 2: global -> bufA(R2)   (NITEM = 5: pairs (0,1),(2,3),(4))
    s2_pair<INT>(tid, 0, gin, bufA, R2.x0, R2.y0, true);
    s2_pair<INT>(tid, 2, gin, bufA, R2.x0, R2.y0, true);
    s2_pair<INT>(tid, 4, gin, bufA, R2.x0, R2.y0, false);
    __syncthreads();
    // stage 3 (scale): bufA(R2) -> bufB(R3)
    stage_lds<W2, H2, W3, W3 * H3, true, INT>(tid,
        1.1f, 0.0f, -25.55f - (float)R2.x0,
        0.0f, 0.95f, 12.775f - (float)R2.y0, bufA, bufB, R3.x0, R3.y0);
    __syncthreads();
    // stage 4 (zoom): bufB(R3) -> bufA(R4)
    stage_lds<W3, H3, W4, W4 * H4, true, INT>(tid,
        0.9f, 0.0f, 25.55f - (float)R3.x0,
        0.0f, 0.9f, 25.55f - (float)R3.y0, bufB, bufA, R4.x0, R4.y0);
    __syncthreads();
    // stage 5 (rotate): bufA(R4) -> bufB(R5)
    stage_lds<W4, H4, W5, W5 * H5, false, INT>(tid,
        CR, -SR, K5CX - (float)R4.x0,
        SR,  CR, K5CY - (float)R4.y0, bufA, bufB, R5.x0, R5.y0);
    __syncthreads();
    // stage 6 (shear): bufB(R5) -> global tiles
    s6_both<INT>(tid, bufB, go, tx0, ty0, R5.x0, R5.y0);
}

// One block per (plane-pair, 32x32 tile): inline nearest-map compose + label
// gather + 6 fused img stages for 2 planes sharing all coordinate math.
__global__ __launch_bounds__(NT, 8) void fused_all(
    const float* __restrict__ img, const float* __restrict__ lab,
    float* __restrict__ oimg, float* __restrict__ olab)
{
    __shared__ float2 bufA[BUFA_SZ];
    __shared__ float2 bufB[BUFB_SZ];
    int tid = threadIdx.x;
    int b = blockIdx.x;
    int group = b >> 8, tile = b & 255;
    int tx0 = (tile & 15) * TS, ty0 = (tile >> 4) * TS;
    int pbase = group * P;
    const float* gin = img + pbase * HW;
    const float* lin = lab + pbase * HW;
    float* go = oimg + pbase * HW;
    float* lo = olab + pbase * HW;

    // ---- label: inline composed nearest map (bit-identical to standalone),
    //      both items batched, one map eval feeds both planes ----
    {
        const float TH[6][6] = {
            { 1.0f,  0.05f, 0.0f,  -0.03f, 1.0f,  0.0f },   // shear
            { CR,    -SR,   0.0f,   SR,    CR,    0.0f },   // rotate
            { 0.9f,  0.0f,  0.0f,   0.0f,  0.9f,  0.0f },   // zoom
            { 1.1f,  0.0f,  0.0f,   0.0f,  0.95f, 0.0f },   // scale
            { 1.0f,  0.0f,  0.06f,  0.0f,  1.0f, -0.04f },  // translate
            { -1.0f, 0.0f,  0.0f,   0.0f,  1.0f,  0.0f },   // mirror
        };
        int m[2]; bool valid[2]; int gidx[2];
        #pragma unroll
        for (int t = 0; t < 2; ++t) {
            int ii = tid + t * NT;
            int lx = ii & 31, ly = ii >> 5;
            int cx = tx0 + lx, cy = ty0 + ly;
            gidx[t] = cy * 512 + cx;
            bool v = true;
            #pragma unroll
            for (int s = 0; s < 6; ++s) {
                float x = ((float)cx + 0.5f) * (2.0f / 512.0f) - 1.0f;
                float y = ((float)cy + 0.5f) * (2.0f / 512.0f) - 1.0f;
                float gx = TH[s][0] * x + TH[s][1] * y + TH[s][2];
                float gy = TH[s][3] * x + TH[s][4] * y + TH[s][5];
                float ix = ((gx + 1.0f) * 512.0f - 1.0f) * 0.5f;
                float iy = ((gy + 1.0f) * 512.0f - 1.0f) * 0.5f;
                float xr = rintf(ix), yr = rintf(iy);
                bool ok = (xr >= 0.0f && xr <= 511.0f && yr >= 0.0f && yr <= 511.0f);
                v = v && ok;
                cx = (int)fminf(fmaxf(xr, 0.0f), 511.0f);
                cy = (int)fminf(fmaxf(yr, 0.0f), 511.0f);
            }
            valid[t] = v;
            m[t] = cy * 512 + cx;
        }
        // batched label loads (4 independent)
        float v00 = valid[0] ? lin[m[0]] : 0.f;
        float v01 = valid[0] ? lin[HW + m[0]] : 0.f;
        float v10 = valid[1] ? lin[m[1]] : 0.f;
        float v11 = valid[1] ? lin[HW + m[1]] : 0.f;
        __builtin_nontemporal_store(v00, &lo[gidx[0]]);
        __builtin_nontemporal_store(v01, &lo[HW + gidx[0]]);
        __builtin_nontemporal_store(v10, &lo[gidx[1]]);
        __builtin_nontemporal_store(v11, &lo[HW + gidx[1]]);
    }

    // ---- region chain (uniform across threads) ----
    Box R6 = {tx0, tx0 + TS - 1, ty0, ty0 + TS - 1};
    Box R5 = back_box(R6, 1.0f, 0.05f, -12.775f, -0.03f, 1.0f, 7.665f);   // shear
    R5.x1 = min(R5.x1, R5.x0 + W5 - 1); R5.y1 = min(R5.y1, R5.y0 + H5 - 1);
    Box R4 = back_box(R5, CR, -SR, K5CX, SR, CR, K5CY);                   // rotate
    R4.x1 = min(R4.x1, R4.x0 + W4 - 1); R4.y1 = min(R4.y1, R4.y0 + H4 - 1);
    Box R3 = back_box(R4, 0.9f, 0.0f, 25.55f, 0.0f, 0.9f, 25.55f);        // zoom
    R3.x1 = min(R3.x1, R3.x0 + W3 - 1); R3.y1 = min(R3.y1, R3.y0 + H3 - 1);
    Box R2 = back_box(R3, 1.1f, 0.0f, -25.55f, 0.0f, 0.95f, 12.775f);     // scale

    bool dead = (R2.x1 < 0 || R2.x0 > 511 || R2.y1 < 0 || R2.y0 > 511)
             || (R3.x1 < 0 || R3.x0 > 511 || R3.y1 < 0 || R3.y0 > 511)
             || (R4.x1 < 0 || R4.x0 > 511 || R4.y1 < 0 || R4.y0 > 511)
             || (R5.x1 < 0 || R5.x0 > 511 || R5.y1 < 0 || R5.y0 > 511);
    if (dead) {
        #pragma unroll
        for (int k = 0; k < (TS * TS) / NT; ++k) {
            int ii = tid + k * NT;
            int gidx = (ty0 + (ii >> 5)) * 512 + tx0 + (ii & 31);
            __builtin_nontemporal_store(0.f, &go[gidx]);
            __builtin_nontemporal_store(0.f, &go[HW + gidx]);
        }
        return;
    }

    // interior: every PADDED region cell has fully-valid taps & coords
    bool interior =
        R2.x0 >= 0 && R2.x0 + W2 - 1 <= 495 && R2.y0 >= 11 && R2.y0 + H2 - 1 <= 511 &&
        R3.x0 >= 0 && R3.x0 + W3 - 1 <= 511 && R3.y0 >= 0 && R3.y0 + H3 - 1 <= 511 &&
        R4.x0 >= 0 && R4.x0 + W4 - 1 <= 511 && R4.y0 >= 0 && R4.y0 + H4 - 1 <= 511 &&
        R5.x0 >= 0 && R5.x0 + W5 - 1 <= 511 && R5.y0 >= 0 && R5.y0 + H5 - 1 <= 511;

    if (interior)
        img_tile<true >(tid, gin, go, tx0, ty0, R2, R3, R4, R5, bufA, bufB);
    else
        img_tile<false>(tid, gin, go, tx0, ty0, R2, R3, R4, R5, bufA, bufB);
}

extern "C" void kernel_launch(void* const* d_in, const int* in_sizes, int n_in,
                              void* d_out, int out_size, void* d_ws, size_t ws_size,
                              hipStream_t stream) {
    const float* img_in = (const float*)d_in[0];
    const float* lab_in = (const float*)d_in[1];
    float* out_img = (float*)d_out;
    float* out_lab = (float*)d_out + TOTAL;
    (void)d_ws; (void)ws_size;

    fused_all<<<NGROUP * 256, NT, 0, stream>>>(img_in, lab_in, out_img, out_lab);
}

// Round 9
// 70.722 us; speedup vs baseline: 1.0935x; 1.0935x over previous
//
#include <hip/hip_runtime.h>
#include <math.h>

#define HW 262144            // 512*512
#define TOTAL 12582912       // 48 planes * HW
#define TS 32
#define NT 512               // threads per block
#define P 2                  // planes per block, element-interleaved as float2
#define NGROUP 24            // 48 / P

#define CR 0.8910065241883679f   // cos(27 deg)
#define SR 0.45399049973954675f  // sin(27 deg)

#define K5CX (255.5f * (1.0f - CR + SR))
#define K5CY (255.5f * (1.0f - SR - CR))

// Fixed padded region dims (>= max true span at any tile position)
#define W2 52
#define H2 44
#define W3 46
#define H3 45
#define W4 49
#define H4 48
#define W5 36
#define H5 35
#define BUFA_SZ 2352   // float2 cells: max(W2*H2=2288, W4*H4=2352)
#define BUFB_SZ 2070   // float2 cells: max(W3*H3=2070, W5*H5=1260)

struct Box { int x0, x1, y0, y1; };

__device__ __forceinline__ Box back_box(Box d, float A, float B, float C,
                                        float D, float E, float F) {
    float xa = (float)d.x0, xb = (float)d.x1, ya = (float)d.y0, yb = (float)d.y1;
    float mnx = fminf(A * xa, A * xb) + fminf(B * ya, B * yb) + C;
    float mxx = fmaxf(A * xa, A * xb) + fmaxf(B * ya, B * yb) + C;
    float mny = fminf(D * xa, D * xb) + fminf(E * ya, E * yb) + F;
    float mxy = fmaxf(D * xa, D * xb) + fmaxf(E * ya, E * yb) + F;
    Box s;
    s.x0 = (int)floorf(mnx); s.x1 = (int)floorf(mxx) + 1;
    s.y0 = (int)floorf(mny); s.y1 = (int)floorf(mxy) + 1;
    return s;
}

__device__ __forceinline__ float2 lerp2(float w, float2 a, float2 b) {
    float2 r;
    r.x = fmaf(w, b.x - a.x, a.x);
    r.y = fmaf(w, b.y - a.y, a.y);
    return r;
}

// ---- geometry for one LDS-stage item ----
template <int SW, int SH, int DW, bool AXIS, bool INT>
__device__ __forceinline__ void lds_geom(int i, float A, float B, float Cs,
    float D, float E, float Fs, int dx0, int dy0,
    int& sbase, float& wx, float& wy, bool& oob)
{
    int ly = i / DW;
    int lx = i - ly * DW;
    int pxi = dx0 + lx, pyi = dy0 + ly;
    float px = (float)pxi, py = (float)pyi;
    float fx = AXIS ? fmaf(A, px, Cs) : fmaf(A, px, fmaf(B, py, Cs));
    float fy = AXIS ? fmaf(E, py, Fs) : fmaf(D, px, fmaf(E, py, Fs));
    float xf = floorf(fx), yf = floorf(fy);
    wx = fx - xf; wy = fy - yf;
    int x0 = (int)xf, y0 = (int)yf;
    if (!INT) { x0 = min(max(x0, 0), SW - 2); y0 = min(max(y0, 0), SH - 2); }
    sbase = y0 * SW + x0;
    oob = (!INT) && ((unsigned)pxi >= 512u || (unsigned)pyi >= 512u);
}

// ---- chunk of CNT items: all geometry -> all LDS reads -> all math/writes ----
template <int SW, int SH, int DW, int DTOT, bool AXIS, bool INT, int K0, int CNT>
__device__ __forceinline__ void lds_chunk(int tid, float A, float B, float Cs,
    float D, float E, float Fs, const float2* __restrict__ src,
    float2* __restrict__ dst, int dx0, int dy0)
{
    int sb[CNT], ci[CNT];
    float wx[CNT], wy[CNT];
    bool oob[CNT], wr[CNT];
    #pragma unroll
    for (int t = 0; t < CNT; ++t) {
        int i = tid + (K0 + t) * NT;
        wr[t] = (i < DTOT);                 // folds to true for full chunks
        int c = wr[t] ? i : (DTOT - 1);
        ci[t] = c;
        lds_geom<SW, SH, DW, AXIS, INT>(c, A, B, Cs, D, E, Fs, dx0, dy0,
                                        sb[t], wx[t], wy[t], oob[t]);
    }
    float2 v00[CNT], v01[CNT], v10[CNT], v11[CNT];
    #pragma unroll
    for (int t = 0; t < CNT; ++t) {
        const float2* s = src + sb[t];
        v00[t] = s[0];  v01[t] = s[1];
        v10[t] = s[SW]; v11[t] = s[SW + 1];
    }
    #pragma unroll
    for (int t = 0; t < CNT; ++t) {
        float2 a0 = lerp2(wx[t], v00[t], v01[t]);
        float2 a1 = lerp2(wx[t], v10[t], v11[t]);
        float2 val = lerp2(wy[t], a0, a1);
        if (!INT && oob[t]) { val.x = 0.f; val.y = 0.f; }
        if (wr[t]) dst[ci[t]] = val;
    }
}

// ---- LDS -> LDS bilinear stage, chunked (depth 3) for read ILP ----
template <int SW, int SH, int DW, int DTOT, bool AXIS, bool INT>
__device__ __forceinline__ void stage_lds(int tid, float A, float B, float Cs,
    float D, float E, float Fs, const float2* __restrict__ src,
    float2* __restrict__ dst, int dx0, int dy0)
{
    constexpr int NITEM = (DTOT + NT - 1) / NT;   // <= 5 for all stages
    constexpr int C0 = (NITEM < 3) ? NITEM : 3;
    lds_chunk<SW, SH, DW, DTOT, AXIS, INT, 0, C0>(tid, A, B, Cs, D, E, Fs,
                                                  src, dst, dx0, dy0);
    if constexpr (NITEM > 3) {
        lds_chunk<SW, SH, DW, DTOT, AXIS, INT, 3, NITEM - 3>(tid, A, B, Cs,
                                                  D, E, Fs, src, dst, dx0, dy0);
    }
}

// ---- stage 2 (translate, mirror folded): global -> bufA (float2), 2 planes ----
// Constant weights wx=0.36, wy=0.76; taps at x = 496-pxi, 495-pxi; rows pyi-11, pyi-10.
template <bool INT>
__device__ __forceinline__ void s2_eval(int i, const float* __restrict__ gin,
                                        float2* __restrict__ dst, int rx0, int ry0)
{
    int ly = i / W2;
    int lx = i - ly * W2;
    int pxi = rx0 + lx, pyi = ry0 + ly;
    if (INT) {
        int off = ((pyi - 11) << 9) + (496 - pxi);
        float2 o;
        {
            const float* g0 = gin + off;
            float h0 = fmaf(0.36f, g0[-1], 0.64f * g0[0]);
            float h1 = fmaf(0.36f, g0[511], 0.64f * g0[512]);
            o.x = fmaf(0.76f, h1, 0.24f * h0);
        }
        {
            const float* g1 = gin + HW + off;
            float h0 = fmaf(0.36f, g1[-1], 0.64f * g1[0]);
            float h1 = fmaf(0.36f, g1[511], 0.64f * g1[512]);
            o.y = fmaf(0.76f, h1, 0.24f * h0);
        }
        dst[i] = o;
    } else {
        float wx0m = ((unsigned)pxi <= 496u) ? 0.64f : 0.0f;
        float wx1m = ((unsigned)pxi <= 495u) ? 0.36f : 0.0f;
        float wy0m = ((unsigned)(pyi - 11) <= 500u) ? 0.24f : 0.0f;
        float wy1m = ((unsigned)(pyi - 10) <= 501u) ? 0.76f : 0.0f;
        int xc0 = min(max(496 - pxi, 0), 511);
        int xc1 = min(max(495 - pxi, 0), 511);
        int r0 = min(max(pyi - 11, 0), 511) << 9;
        int r1 = min(max(pyi - 10, 0), 511) << 9;
        float2 o;
        #pragma unroll
        for (int p = 0; p < P; ++p) {
            const float* g = gin + p * HW;
            float v00 = g[r0 + xc0], v01 = g[r0 + xc1];
            float v10 = g[r1 + xc0], v11 = g[r1 + xc1];
            float h0 = fmaf(wx1m, v01, wx0m * v00);
            float h1 = fmaf(wx1m, v11, wx0m * v10);
            float val = fmaf(wy1m, h1, wy0m * h0);
            if (p == 0) o.x = val; else o.y = val;
        }
        dst[i] = o;
    }
}

// ---- stage 6 (shear): bufB(R5, float2) -> global, both items batched ----
template <bool INT>
__device__ __forceinline__ void s6_both(int tid, const float2* __restrict__ src,
    float* __restrict__ go, int tx0, int ty0, int sx0, int sy0)
{
    float Csx = -12.775f - (float)sx0;
    float Fsy = 7.665f - (float)sy0;
    int s[2]; float wx[2], wy[2]; int gidx[2];
    #pragma unroll
    for (int t = 0; t < 2; ++t) {
        int ii = tid + t * NT;
        int lx = ii & 31, ly = ii >> 5;
        float px = (float)(tx0 + lx), py = (float)(ty0 + ly);
        float fx = fmaf(0.05f, py, Csx) + px;
        float fy = fmaf(-0.03f, px, Fsy) + py;
        float xf = floorf(fx), yf = floorf(fy);
        wx[t] = fx - xf; wy[t] = fy - yf;
        int x0 = (int)xf, y0 = (int)yf;
        if (!INT) { x0 = min(max(x0, 0), W5 - 2); y0 = min(max(y0, 0), H5 - 2); }
        s[t] = y0 * W5 + x0;
        gidx[t] = (ty0 + ly) * 512 + tx0 + lx;
    }
    float2 q00 = src[s[0]], q01 = src[s[0] + 1];
    float2 q10 = src[s[0] + W5], q11 = src[s[0] + W5 + 1];
    float2 r00 = src[s[1]], r01 = src[s[1] + 1];
    float2 r10 = src[s[1] + W5], r11 = src[s[1] + W5 + 1];
    {
        float2 a0 = lerp2(wx[0], q00, q01);
        float2 a1 = lerp2(wx[0], q10, q11);
        float2 val = lerp2(wy[0], a0, a1);
        __builtin_nontemporal_store(val.x, &go[gidx[0]]);
        __builtin_nontemporal_store(val.y, &go[HW + gidx[0]]);
    }
    {
        float2 a0 = lerp2(wx[1], r00, r01);
        float2 a1 = lerp2(wx[1], r10, r11);
        float2 val = lerp2(wy[1], a0, a1);
        __builtin_nontemporal_store(val.x, &go[gidx[1]]);
        __builtin_nontemporal_store(val.y, &go[HW + gidx[1]]);
    }
}

// ---- full img tile pipeline for 2 interleaved planes ----
template <bool INT>
__device__ __forceinline__ void img_tile(int tid, const float* __restrict__ gin,
    float* __restrict__ go, int tx0, int ty0,
    Box R2, Box R3, Box R4, Box R5, float2* bufA, float2* bufB)
{
    // stage 2: global -> bufA(R2)
    {
        constexpr int FULL = (W2 * H2) / NT;
        constexpr int TAIL = W2 * H2 - FULL * NT;
        #pragma unroll
        for (int k = 0; k < FULL; ++k)
            s2_eval<INT>(tid + k * NT, gin, bufA, R2.x0, R2.y0);
        if (tid < TAIL) s2_eval<INT>(tid + FULL * NT, gin, bufA, R2.x0, R2.y0);
    }
    __syncthreads();
    // stage 3 (scale): bufA(R2) -> bufB(R3)
    stage_lds<W2, H2, W3, W3 * H3, true, INT>(tid,
        1.1f, 0.0f, -25.55f - (float)R2.x0,
        0.0f, 0.95f, 12.775f - (float)R2.y0, bufA, bufB, R3.x0, R3.y0);
    __syncthreads();
    // stage 4 (zoom): bufB(R3) -> bufA(R4)
    stage_lds<W3, H3, W4, W4 * H4, true, INT>(tid,
        0.9f, 0.0f, 25.55f - (float)R3.x0,
        0.0f, 0.9f, 25.55f - (float)R3.y0, bufB, bufA, R4.x0, R4.y0);
    __syncthreads();
    // stage 5 (rotate): bufA(R4) -> bufB(R5)
    stage_lds<W4, H4, W5, W5 * H5, false, INT>(tid,
        CR, -SR, K5CX - (float)R4.x0,
        SR,  CR, K5CY - (float)R4.y0, bufA, bufB, R5.x0, R5.y0);
    __syncthreads();
    // stage 6 (shear): bufB(R5) -> global tiles
    s6_both<INT>(tid, bufB, go, tx0, ty0, R5.x0, R5.y0);
}

// Compose the 6 nearest-neighbor integer maps (exact vs sequential resampling).
__global__ void compose_nearest_map(int* __restrict__ map) {
    int p = blockIdx.x * blockDim.x + threadIdx.x;
    if (p >= HW) return;
    const float TH[6][6] = {
        { 1.0f,  0.05f, 0.0f,  -0.03f, 1.0f,  0.0f },   // shear
        { CR,    -SR,   0.0f,   SR,    CR,    0.0f },   // rotate
        { 0.9f,  0.0f,  0.0f,   0.0f,  0.9f,  0.0f },   // zoom
        { 1.1f,  0.0f,  0.0f,   0.0f,  0.95f, 0.0f },   // scale
        { 1.0f,  0.0f,  0.06f,  0.0f,  1.0f, -0.04f },  // translate
        { -1.0f, 0.0f,  0.0f,   0.0f,  1.0f,  0.0f },   // mirror
    };
    int cx = p & 511, cy = p >> 9;
    bool valid = true;
    #pragma unroll
    for (int s = 0; s < 6; ++s) {
        if (!valid) break;
        float x = (cx + 0.5f) * (2.0f / 512.0f) - 1.0f;
        float y = (cy + 0.5f) * (2.0f / 512.0f) - 1.0f;
        float gx = TH[s][0] * x + TH[s][1] * y + TH[s][2];
        float gy = TH[s][3] * x + TH[s][4] * y + TH[s][5];
        float ix = ((gx + 1.0f) * 512.0f - 1.0f) * 0.5f;
        float iy = ((gy + 1.0f) * 512.0f - 1.0f) * 0.5f;
        float xr = rintf(ix), yr = rintf(iy);
        if (xr < 0.0f || xr > 511.0f || yr < 0.0f || yr > 511.0f) valid = false;
        else { cx = (int)xr; cy = (int)yr; }
    }
    map[p] = valid ? (cy * 512 + cx) : -1;
}

// One block per (plane-pair, 32x32 tile): label gather + 6 fused img stages
// for 2 planes sharing all coordinate math, interleaved as float2 in LDS.
__global__ __launch_bounds__(NT, 8) void fused_all(
    const float* __restrict__ img, const float* __restrict__ lab,
    const int* __restrict__ map, float* __restrict__ oimg,
    float* __restrict__ olab)
{
    __shared__ float2 bufA[BUFA_SZ];
    __shared__ float2 bufB[BUFB_SZ];
    int tid = threadIdx.x;
    int b = blockIdx.x;
    int group = b >> 8, tile = b & 255;
    int tx0 = (tile & 15) * TS, ty0 = (tile >> 4) * TS;
    int pbase = group * P;
    const float* gin = img + pbase * HW;
    const float* lin = lab + pbase * HW;
    float* go = oimg + pbase * HW;
    float* lo = olab + pbase * HW;

    // ---- label tiles: one map read feeds both planes; both items batched ----
    {
        int m0, m1, g0, g1;
        {
            int ii = tid;
            g0 = (ty0 + (ii >> 5)) * 512 + tx0 + (ii & 31);
            int jj = tid + NT;
            g1 = (ty0 + (jj >> 5)) * 512 + tx0 + (jj & 31);
        }
        m0 = map[g0]; m1 = map[g1];
        float v00 = (m0 >= 0) ? lin[m0] : 0.f;
        float v01 = (m0 >= 0) ? lin[HW + m0] : 0.f;
        float v10 = (m1 >= 0) ? lin[m1] : 0.f;
        float v11 = (m1 >= 0) ? lin[HW + m1] : 0.f;
        __builtin_nontemporal_store(v00, &lo[g0]);
        __builtin_nontemporal_store(v01, &lo[HW + g0]);
        __builtin_nontemporal_store(v10, &lo[g1]);
        __builtin_nontemporal_store(v11, &lo[HW + g1]);
    }

    // ---- region chain (uniform across threads) ----
    Box R6 = {tx0, tx0 + TS - 1, ty0, ty0 + TS - 1};
    Box R5 = back_box(R6, 1.0f, 0.05f, -12.775f, -0.03f, 1.0f, 7.665f);   // shear
    R5.x1 = min(R5.x1, R5.x0 + W5 - 1); R5.y1 = min(R5.y1, R5.y0 + H5 - 1);
    Box R4 = back_box(R5, CR, -SR, K5CX, SR, CR, K5CY);                   // rotate
    R4.x1 = min(R4.x1, R4.x0 + W4 - 1); R4.y1 = min(R4.y1, R4.y0 + H4 - 1);
    Box R3 = back_box(R4, 0.9f, 0.0f, 25.55f, 0.0f, 0.9f, 25.55f);        // zoom
    R3.x1 = min(R3.x1, R3.x0 + W3 - 1); R3.y1 = min(R3.y1, R3.y0 + H3 - 1);
    Box R2 = back_box(R3, 1.1f, 0.0f, -25.55f, 0.0f, 0.95f, 12.775f);     // scale

    bool dead = (R2.x1 < 0 || R2.x0 > 511 || R2.y1 < 0 || R2.y0 > 511)
             || (R3.x1 < 0 || R3.x0 > 511 || R3.y1 < 0 || R3.y0 > 511)
             || (R4.x1 < 0 || R4.x0 > 511 || R4.y1 < 0 || R4.y0 > 511)
             || (R5.x1 < 0 || R5.x0 > 511 || R5.y1 < 0 || R5.y0 > 511);
    if (dead) {
        #pragma unroll
        for (int k = 0; k < (TS * TS) / NT; ++k) {
            int ii = tid + k * NT;
            int gidx = (ty0 + (ii >> 5)) * 512 + tx0 + (ii & 31);
            __builtin_nontemporal_store(0.f, &go[gidx]);
            __builtin_nontemporal_store(0.f, &go[HW + gidx]);
        }
        return;
    }

    // interior: every PADDED region cell has fully-valid taps & coords
    bool interior =
        R2.x0 >= 0 && R2.x0 + W2 - 1 <= 495 && R2.y0 >= 11 && R2.y0 + H2 - 1 <= 511 &&
        R3.x0 >= 0 && R3.x0 + W3 - 1 <= 511 && R3.y0 >= 0 && R3.y0 + H3 - 1 <= 511 &&
        R4.x0 >= 0 && R4.x0 + W4 - 1 <= 511 && R4.y0 >= 0 && R4.y0 + H4 - 1 <= 511 &&
        R5.x0 >= 0 && R5.x0 + W5 - 1 <= 511 && R5.y0 >= 0 && R5.y0 + H5 - 1 <= 511;

    if (interior)
        img_tile<true >(tid, gin, go, tx0, ty0, R2, R3, R4, R5, bufA, bufB);
    else
        img_tile<false>(tid, gin, go, tx0, ty0, R2, R3, R4, R5, bufA, bufB);
}

extern "C" void kernel_launch(void* const* d_in, const int* in_sizes, int n_in,
                              void* d_out, int out_size, void* d_ws, size_t ws_size,
                              hipStream_t stream) {
    const float* img_in = (const float*)d_in[0];
    const float* lab_in = (const float*)d_in[1];
    float* out_img = (float*)d_out;
    float* out_lab = (float*)d_out + TOTAL;
    int* map = (int*)d_ws;

    compose_nearest_map<<<(HW + 255) / 256, 256, 0, stream>>>(map);
    fused_all<<<NGROUP * 256, NT, 0, stream>>>(img_in, lab_in, map, out_img, out_lab);
}